// Round 1
// baseline (778.403 us; speedup 1.0000x reference)
//
#include <hip/hip_runtime.h>
#include <hip/hip_bf16.h>

// Problem constants
#define B_    16
#define CI    512
#define CO    512
#define HH    64
#define WW    64
#define NPIX  4096          // 64*64
#define KTAPS 9
#define KTOT  (CI * KTAPS)  // 4608
#define LEAK  0.2f

// Padded channels-last image: [b][66][66][512] bf16 (1-px halo absorbs SAME pad)
#define PY 66
#define PX 66
#define IMGPAD_ELEMS ((size_t)B_ * PY * PX * CI)

typedef __attribute__((ext_vector_type(8))) __bf16  bf16x8;
typedef __attribute__((ext_vector_type(4))) float   floatx4;

// ---------------------------------------------------------------- prep kernels

// style[b][i] = sum_w w_embs[b][w] * style_w[i][w] + style_b[i] + 1
__global__ void style_kernel(const float* __restrict__ w_embs,
                             const float* __restrict__ style_w,
                             const float* __restrict__ style_b,
                             float* __restrict__ style) {
    int b = blockIdx.y;
    int i = blockIdx.x * 256 + threadIdx.x;
    const float4* we = (const float4*)(w_embs + (size_t)b * 512);
    const float4* sw = (const float4*)(style_w + (size_t)i * 512);
    float acc = 0.f;
    #pragma unroll 8
    for (int k = 0; k < 128; ++k) {
        float4 a = we[k], c = sw[k];
        acc += a.x * c.x + a.y * c.y + a.z * c.z + a.w * c.w;
    }
    style[b * 512 + i] = acc + style_b[i] + 1.0f;
}

// w2[o][i] = sum_tap conv_w[o][i][tap]^2
__global__ void w2_kernel(const float* __restrict__ conv_w, float* __restrict__ w2) {
    int idx = blockIdx.x * 256 + threadIdx.x;   // o*512+i, 262144 total
    const float* p = conv_w + (size_t)idx * 9;
    float s = 0.f;
    #pragma unroll
    for (int t = 0; t < 9; ++t) s += p[t] * p[t];
    w2[idx] = s;
}

// invn[b][o] = 1/sqrt( sum_i w2[o][i] * style[b][i]^2 )
__global__ void invn_kernel(const float* __restrict__ w2,
                            const float* __restrict__ style,
                            float* __restrict__ invn) {
    __shared__ float st2[512];
    int b = blockIdx.y;
    int o = blockIdx.x * 256 + threadIdx.x;
    for (int i = threadIdx.x; i < 512; i += 256) {
        float s = style[b * 512 + i];
        st2[i] = s * s;
    }
    __syncthreads();
    const float* wr = w2 + (size_t)o * 512;
    float acc = 0.f;
    #pragma unroll 8
    for (int i = 0; i < 512; ++i) acc += wr[i] * st2[i];
    invn[b * 512 + o] = 1.0f / sqrtf(acc);
}

// wmod[b][o][tap*512 + i] = bf16( conv_w[o][i][tap] * style[b][i] * invn[b][o] )
__global__ void wmod_kernel(const float* __restrict__ conv_w,
                            const float* __restrict__ style,
                            const float* __restrict__ invn,
                            __bf16* __restrict__ wmod) {
    int o = blockIdx.x, b = blockIdx.y, i = threadIdx.x;   // block = 512
    float s = style[b * 512 + i] * invn[b * 512 + o];
    const float* p = conv_w + ((size_t)o * 512 + i) * 9;
    __bf16* dst = wmod + ((size_t)(b * 512 + o)) * KTOT + i;
    #pragma unroll
    for (int t = 0; t < 9; ++t) dst[t * 512] = (__bf16)(p[t] * s);
}

// NCHW fp32 -> padded channels-last bf16 [b][y][x][i]; interior only (halo pre-zeroed)
__global__ void imgpad_kernel(const float* __restrict__ imgs,
                              __bf16* __restrict__ imgpad) {
    __shared__ float tile[32][65];
    int ic = blockIdx.x, h = blockIdx.y, b = blockIdx.z;
    int t = threadIdx.x;
    int i0 = ic * 32;
    {
        int li = t >> 3;            // 0..31 channel within chunk
        int w0 = (t & 7) * 8;       // 0..56
        const float* src = imgs + (((size_t)(b * 512 + i0 + li) * 64 + h) * 64 + w0);
        float4 v0 = ((const float4*)src)[0];
        float4 v1 = ((const float4*)src)[1];
        tile[li][w0 + 0] = v0.x; tile[li][w0 + 1] = v0.y;
        tile[li][w0 + 2] = v0.z; tile[li][w0 + 3] = v0.w;
        tile[li][w0 + 4] = v1.x; tile[li][w0 + 5] = v1.y;
        tile[li][w0 + 6] = v1.z; tile[li][w0 + 7] = v1.w;
    }
    __syncthreads();
    {
        int w  = t >> 2;            // 0..63
        int c0 = (t & 3) * 8;       // 0,8,16,24
        bf16x8 v;
        #pragma unroll
        for (int j = 0; j < 8; ++j) v[j] = (__bf16)tile[c0 + j][w];
        __bf16* dst = imgpad + (((size_t)b * PY + (h + 1)) * PX + (w + 1)) * 512 + i0 + c0;
        *(bf16x8*)dst = v;
    }
}

// ---------------------------------------------------------------- main conv

#define BM 128
#define BN 128
#define BK 32
#define LDK 40   // +8 bf16 pad: rows stay 16B-aligned, breaks pow-2 bank stride

__global__ __launch_bounds__(256) void conv_kernel(
    const __bf16* __restrict__ wmod,
    const __bf16* __restrict__ imgpad,
    const float*  __restrict__ conv_b,
    const float*  __restrict__ noise,
    const float*  __restrict__ nw_p,
    float* __restrict__ out)
{
    __shared__ __attribute__((aligned(16))) __bf16 As[BM][LDK];
    __shared__ __attribute__((aligned(16))) __bf16 Bs[BN][LDK];

    int tid = threadIdx.x;
    int nt = blockIdx.x, mt = blockIdx.y, b = blockIdx.z;
    int n0 = nt * BN, m0 = mt * BM;

    const __bf16* wB = wmod + ((size_t)b * CO + m0) * KTOT;
    const __bf16* iB = imgpad + (size_t)b * PY * PX * CI;

    // staging coords: 512 vec8 per tile, 2 per thread
    int v0 = tid, v1 = tid + 256;
    int row0 = v0 >> 2, row1 = v1 >> 2;          // A-row (=o) and B-row (=pixel n)
    int kq0 = (v0 & 3) * 8, kq1 = (v1 & 3) * 8;
    int p0 = n0 + row0, p1 = n0 + row1;
    int h0 = p0 >> 6, w0 = p0 & 63;
    int h1 = p1 >> 6, w1 = p1 & 63;

    floatx4 acc[4][4];
    #pragma unroll
    for (int mi = 0; mi < 4; ++mi)
        #pragma unroll
        for (int ni = 0; ni < 4; ++ni)
            acc[mi][ni] = (floatx4)(0.f);

    int lane = tid & 63;
    int wv = tid >> 6;
    int wm = (wv & 1) * 64, wn = (wv >> 1) * 64;
    int q = lane >> 4, r = lane & 15;

    for (int tap = 0; tap < 9; ++tap) {
        int dy = tap / 3, dx = tap % 3;
        const __bf16* aBase0 = wB + (size_t)row0 * KTOT + tap * 512 + kq0;
        const __bf16* aBase1 = wB + (size_t)row1 * KTOT + tap * 512 + kq1;
        const __bf16* bBase0 = iB + ((size_t)(h0 + dy) * PX + (w0 + dx)) * 512 + kq0;
        const __bf16* bBase1 = iB + ((size_t)(h1 + dy) * PX + (w1 + dx)) * 512 + kq1;
        for (int ic = 0; ic < 16; ++ic) {
            int ko = ic * 32;
            bf16x8 a0 = *(const bf16x8*)(aBase0 + ko);
            bf16x8 a1 = *(const bf16x8*)(aBase1 + ko);
            bf16x8 g0 = *(const bf16x8*)(bBase0 + ko);
            bf16x8 g1 = *(const bf16x8*)(bBase1 + ko);
            __syncthreads();   // previous iter's fragment reads complete
            *(bf16x8*)&As[row0][kq0] = a0;
            *(bf16x8*)&As[row1][kq1] = a1;
            *(bf16x8*)&Bs[row0][kq0] = g0;
            *(bf16x8*)&Bs[row1][kq1] = g1;
            __syncthreads();
            bf16x8 af[4], bfr[4];
            #pragma unroll
            for (int mi = 0; mi < 4; ++mi)
                af[mi] = *(const bf16x8*)&As[wm + mi * 16 + r][q * 8];
            #pragma unroll
            for (int ni = 0; ni < 4; ++ni)
                bfr[ni] = *(const bf16x8*)&Bs[wn + ni * 16 + r][q * 8];
            #pragma unroll
            for (int mi = 0; mi < 4; ++mi)
                #pragma unroll
                for (int ni = 0; ni < 4; ++ni)
                    acc[mi][ni] = __builtin_amdgcn_mfma_f32_16x16x32_bf16(
                        af[mi], bfr[ni], acc[mi][ni], 0, 0, 0);
        }
    }

    // epilogue: + conv_b + noise*nw, LeakyReLU(0.2)
    float nwv = nw_p[0];
    #pragma unroll
    for (int ni = 0; ni < 4; ++ni) {
        int col = n0 + wn + ni * 16 + r;                 // pixel
        float nz = noise[b * NPIX + col] * nwv;
        #pragma unroll
        for (int mi = 0; mi < 4; ++mi) {
            int rowo = m0 + wm + mi * 16 + q * 4;        // output channel base
            #pragma unroll
            for (int rr = 0; rr < 4; ++rr) {
                float vv = acc[mi][ni][rr] + conv_b[rowo + rr] + nz;
                out[(((size_t)b * CO + rowo + rr) << 12) + col] = vv >= 0.f ? vv : LEAK * vv;
            }
        }
    }
}

// ---------------------------------------------------------------- launch

extern "C" void kernel_launch(void* const* d_in, const int* in_sizes, int n_in,
                              void* d_out, int out_size, void* d_ws, size_t ws_size,
                              hipStream_t stream) {
    const float* imgs    = (const float*)d_in[0];
    const float* w_embs  = (const float*)d_in[1];
    const float* noise   = (const float*)d_in[2];
    const float* conv_w  = (const float*)d_in[3];
    const float* conv_b  = (const float*)d_in[4];
    const float* style_w = (const float*)d_in[5];
    const float* style_b = (const float*)d_in[6];
    const float* nw      = (const float*)d_in[7];
    float* out = (float*)d_out;

    char* ws = (char*)d_ws;
    size_t off = 0;
    __bf16* wmod = (__bf16*)(ws + off);      off += (size_t)B_ * CO * KTOT * 2;      // 75.5 MB
    __bf16* imgpad = (__bf16*)(ws + off);    off += IMGPAD_ELEMS * 2;                // 71.4 MB
    float* style = (float*)(ws + off);       off += (size_t)B_ * CI * 4;
    float* invn  = (float*)(ws + off);       off += (size_t)B_ * CO * 4;
    float* w2    = (float*)(ws + off);       off += (size_t)CO * CI * 4;

    hipMemsetAsync(imgpad, 0, IMGPAD_ELEMS * 2, stream);  // halo zeros
    style_kernel<<<dim3(2, B_), 256, 0, stream>>>(w_embs, style_w, style_b, style);
    w2_kernel<<<dim3(1024), 256, 0, stream>>>(conv_w, w2);
    invn_kernel<<<dim3(2, B_), 256, 0, stream>>>(w2, style, invn);
    wmod_kernel<<<dim3(CO, B_), 512, 0, stream>>>(conv_w, style, invn, wmod);
    imgpad_kernel<<<dim3(16, HH, B_), 256, 0, stream>>>(imgs, imgpad);
    conv_kernel<<<dim3(NPIX / BN, CO / BM, B_), 256, 0, stream>>>(
        wmod, imgpad, conv_b, noise, nw, out);
}

// Round 2
// 766.928 us; speedup vs baseline: 1.0150x; 1.0150x over previous
//
#include <hip/hip_runtime.h>
#include <hip/hip_bf16.h>

// Problem constants
#define B_    16
#define CI    512
#define CO    512
#define HH    64
#define WW    64
#define NPIX  4096          // 64*64
#define KTAPS 9
#define KTOT  (CI * KTAPS)  // 4608
#define LEAK  0.2f

// Padded channels-last image: [b][66][66][512] bf16 (1-px halo absorbs SAME pad)
#define PY 66
#define PX 66
#define IMGPAD_ELEMS ((size_t)B_ * PY * PX * CI)

typedef __attribute__((ext_vector_type(8))) __bf16  bf16x8;
typedef __attribute__((ext_vector_type(4))) float   floatx4;

// Direct global->LDS 16B staging (m97 pattern). LDS dest is wave-uniform
// base + lane*16; global addr is per-lane.
__device__ __forceinline__ void load_lds16(const __bf16* g, __bf16* l) {
    __builtin_amdgcn_global_load_lds(
        (const __attribute__((address_space(1))) unsigned int*)g,
        (__attribute__((address_space(3))) unsigned int*)(unsigned int)(uintptr_t)l,
        16, 0, 0);
}

// ---------------------------------------------------------------- prep kernels

// style[b][i] = sum_w w_embs[b][w] * style_w[i][w] + style_b[i] + 1
__global__ void style_kernel(const float* __restrict__ w_embs,
                             const float* __restrict__ style_w,
                             const float* __restrict__ style_b,
                             float* __restrict__ style) {
    int b = blockIdx.y;
    int i = blockIdx.x * 256 + threadIdx.x;
    const float4* we = (const float4*)(w_embs + (size_t)b * 512);
    const float4* sw = (const float4*)(style_w + (size_t)i * 512);
    float acc = 0.f;
    #pragma unroll 8
    for (int k = 0; k < 128; ++k) {
        float4 a = we[k], c = sw[k];
        acc += a.x * c.x + a.y * c.y + a.z * c.z + a.w * c.w;
    }
    style[b * 512 + i] = acc + style_b[i] + 1.0f;
}

// w2[o][i] = sum_tap conv_w[o][i][tap]^2
__global__ void w2_kernel(const float* __restrict__ conv_w, float* __restrict__ w2) {
    int idx = blockIdx.x * 256 + threadIdx.x;   // o*512+i, 262144 total
    const float* p = conv_w + (size_t)idx * 9;
    float s = 0.f;
    #pragma unroll
    for (int t = 0; t < 9; ++t) s += p[t] * p[t];
    w2[idx] = s;
}

// invn[b][o] = 1/sqrt( sum_i w2[o][i] * style[b][i]^2 )
__global__ void invn_kernel(const float* __restrict__ w2,
                            const float* __restrict__ style,
                            float* __restrict__ invn) {
    __shared__ float st2[512];
    int b = blockIdx.y;
    int o = blockIdx.x * 256 + threadIdx.x;
    for (int i = threadIdx.x; i < 512; i += 256) {
        float s = style[b * 512 + i];
        st2[i] = s * s;
    }
    __syncthreads();
    const float* wr = w2 + (size_t)o * 512;
    float acc = 0.f;
    #pragma unroll 8
    for (int i = 0; i < 512; ++i) acc += wr[i] * st2[i];
    invn[b * 512 + o] = 1.0f / sqrtf(acc);
}

// wmod[b][o][tap*512 + i] = bf16( conv_w[o][i][tap] * style[b][i] * invn[b][o] )
// Coalesced: thread owns (o, i0..i0+7); reads 72 contiguous floats, writes 9 x 16B.
__global__ void wmod_kernel(const float* __restrict__ conv_w,
                            const float* __restrict__ style,
                            const float* __restrict__ invn,
                            __bf16* __restrict__ wmod) {
    int b = blockIdx.y;
    int o = blockIdx.x * 4 + (threadIdx.x >> 6);
    int i0 = (threadIdx.x & 63) * 8;
    float inv = invn[b * 512 + o];
    float s[8];
    #pragma unroll
    for (int j = 0; j < 8; ++j) s[j] = style[b * 512 + i0 + j] * inv;
    const float* p = conv_w + ((size_t)o * 512 + i0) * 9;   // 72 contiguous floats
    float w[8][9];
    #pragma unroll
    for (int j = 0; j < 8; ++j)
        #pragma unroll
        for (int t = 0; t < 9; ++t) w[j][t] = p[j * 9 + t];
    __bf16* dstB = wmod + ((size_t)(b * 512 + o)) * KTOT + i0;
    #pragma unroll
    for (int t = 0; t < 9; ++t) {
        bf16x8 v;
        #pragma unroll
        for (int j = 0; j < 8; ++j) v[j] = (__bf16)(w[j][t] * s[j]);
        *(bf16x8*)(dstB + t * 512) = v;
    }
}

// Zero only the halo ring of imgpad (260 px/batch instead of 71 MB memset)
__global__ void halo_kernel(__bf16* __restrict__ imgpad) {
    int t = blockIdx.x * 256 + threadIdx.x;
    if (t >= B_ * 260 * 64) return;
    int c8 = t & 63;
    int rest = t >> 6;
    int px = rest % 260;
    int b = rest / 260;
    int y, x;
    if (px < 66)       { y = 0;  x = px; }
    else if (px < 132) { y = 65; x = px - 66; }
    else { int s = px - 132; y = 1 + (s >> 1); x = (s & 1) * 65; }
    float4 z = {0.f, 0.f, 0.f, 0.f};
    *(float4*)&imgpad[(((size_t)b * PY + y) * PX + x) * 512 + c8 * 8] = z;
}

// NCHW fp32 -> padded channels-last bf16 [b][y][x][i]; interior only
__global__ void imgpad_kernel(const float* __restrict__ imgs,
                              __bf16* __restrict__ imgpad) {
    __shared__ float tile[32][65];
    int ic = blockIdx.x, h = blockIdx.y, b = blockIdx.z;
    int t = threadIdx.x;
    int i0 = ic * 32;
    {
        int li = t >> 3;            // 0..31 channel within chunk
        int w0 = (t & 7) * 8;       // 0..56
        const float* src = imgs + (((size_t)(b * 512 + i0 + li) * 64 + h) * 64 + w0);
        float4 v0 = ((const float4*)src)[0];
        float4 v1 = ((const float4*)src)[1];
        tile[li][w0 + 0] = v0.x; tile[li][w0 + 1] = v0.y;
        tile[li][w0 + 2] = v0.z; tile[li][w0 + 3] = v0.w;
        tile[li][w0 + 4] = v1.x; tile[li][w0 + 5] = v1.y;
        tile[li][w0 + 6] = v1.z; tile[li][w0 + 7] = v1.w;
    }
    __syncthreads();
    {
        int w  = t >> 2;            // 0..63
        int c0 = (t & 3) * 8;       // 0,8,16,24
        bf16x8 v;
        #pragma unroll
        for (int j = 0; j < 8; ++j) v[j] = (__bf16)tile[c0 + j][w];
        __bf16* dst = imgpad + (((size_t)b * PY + (h + 1)) * PX + (w + 1)) * 512 + i0 + c0;
        *(bf16x8*)dst = v;
    }
}

// ---------------------------------------------------------------- main conv

#define BM 128
#define BN 128
#define BK 32

__global__ __launch_bounds__(256) void conv_kernel(
    const __bf16* __restrict__ wmod,
    const __bf16* __restrict__ imgpad,
    const float*  __restrict__ conv_b,
    const float*  __restrict__ noise,
    const float*  __restrict__ nw_p,
    float* __restrict__ out)
{
    // Unpadded, lane-ordered (global_load_lds requires contiguous lane layout)
    __shared__ __attribute__((aligned(16))) __bf16 As[BM * BK];
    __shared__ __attribute__((aligned(16))) __bf16 Bs[BN * BK];

    int tid = threadIdx.x;
    int nt = blockIdx.x, mt = blockIdx.y, b = blockIdx.z;
    int n0 = nt * BN, m0 = mt * BM;

    const __bf16* wB = wmod + ((size_t)b * CO + m0) * KTOT;
    const __bf16* iB = imgpad + (size_t)b * PY * PX * CI;

    int lane = tid & 63;
    int wv = tid >> 6;
    int wm = (wv & 1) * 64, wn = (wv >> 1) * 64;
    int q = lane >> 4, r = lane & 15;

    // staging: wave wv handles 16-row segments wv and wv+4 of each tile.
    // lane l -> row = seg*16 + (l>>2), k8 = (l&3)*8  (matches LDS base+lane*16)
    int sRow = lane >> 2;
    int sK8  = (lane & 3) * 8;
    int aRow0 = wv * 16 + sRow;
    int aRow1 = (wv + 4) * 16 + sRow;
    const __bf16* aG0 = wB + (size_t)aRow0 * KTOT + sK8;
    const __bf16* aG1 = wB + (size_t)aRow1 * KTOT + sK8;
    int p0 = n0 + aRow0, p1 = n0 + aRow1;
    int h0 = p0 >> 6, w0 = p0 & 63;
    int h1 = p1 >> 6, w1 = p1 & 63;

    __bf16* ldsA0 = &As[(wv * 16) * BK];
    __bf16* ldsA1 = &As[((wv + 4) * 16) * BK];
    __bf16* ldsB0 = &Bs[(wv * 16) * BK];
    __bf16* ldsB1 = &Bs[((wv + 4) * 16) * BK];

    floatx4 acc[4][4];
    #pragma unroll
    for (int mi = 0; mi < 4; ++mi)
        #pragma unroll
        for (int ni = 0; ni < 4; ++ni)
            acc[mi][ni] = (floatx4)(0.f);

    for (int tap = 0; tap < 9; ++tap) {
        int dy = tap / 3, dx = tap % 3;
        const __bf16* a0 = aG0 + tap * 512;
        const __bf16* a1 = aG1 + tap * 512;
        const __bf16* b0 = iB + ((size_t)(h0 + dy) * PX + (w0 + dx)) * 512 + sK8;
        const __bf16* b1 = iB + ((size_t)(h1 + dy) * PX + (w1 + dx)) * 512 + sK8;
        for (int ic = 0; ic < 16; ++ic) {
            int ko = ic * 32;
            __syncthreads();               // prior chunk's ds_reads complete
            load_lds16(a0 + ko, ldsA0);
            load_lds16(a1 + ko, ldsA1);
            load_lds16(b0 + ko, ldsB0);
            load_lds16(b1 + ko, ldsB1);
            __syncthreads();               // vmcnt(0) drain -> data visible
            bf16x8 af[4], bfr[4];
            #pragma unroll
            for (int mi = 0; mi < 4; ++mi)
                af[mi] = *(const bf16x8*)&As[(wm + mi * 16 + r) * BK + q * 8];
            #pragma unroll
            for (int ni = 0; ni < 4; ++ni)
                bfr[ni] = *(const bf16x8*)&Bs[(wn + ni * 16 + r) * BK + q * 8];
            #pragma unroll
            for (int mi = 0; mi < 4; ++mi)
                #pragma unroll
                for (int ni = 0; ni < 4; ++ni)
                    acc[mi][ni] = __builtin_amdgcn_mfma_f32_16x16x32_bf16(
                        af[mi], bfr[ni], acc[mi][ni], 0, 0, 0);
        }
    }

    // epilogue: + conv_b + noise*nw, LeakyReLU(0.2)
    float nwv = nw_p[0];
    #pragma unroll
    for (int ni = 0; ni < 4; ++ni) {
        int col = n0 + wn + ni * 16 + r;                 // pixel
        float nz = noise[b * NPIX + col] * nwv;
        #pragma unroll
        for (int mi = 0; mi < 4; ++mi) {
            int rowo = m0 + wm + mi * 16 + q * 4;        // output channel base
            #pragma unroll
            for (int rr = 0; rr < 4; ++rr) {
                float vv = acc[mi][ni][rr] + conv_b[rowo + rr] + nz;
                out[(((size_t)b * CO + rowo + rr) << 12) + col] = vv >= 0.f ? vv : LEAK * vv;
            }
        }
    }
}

// ---------------------------------------------------------------- launch

extern "C" void kernel_launch(void* const* d_in, const int* in_sizes, int n_in,
                              void* d_out, int out_size, void* d_ws, size_t ws_size,
                              hipStream_t stream) {
    const float* imgs    = (const float*)d_in[0];
    const float* w_embs  = (const float*)d_in[1];
    const float* noise   = (const float*)d_in[2];
    const float* conv_w  = (const float*)d_in[3];
    const float* conv_b  = (const float*)d_in[4];
    const float* style_w = (const float*)d_in[5];
    const float* style_b = (const float*)d_in[6];
    const float* nw      = (const float*)d_in[7];
    float* out = (float*)d_out;

    char* ws = (char*)d_ws;
    size_t off = 0;
    __bf16* wmod = (__bf16*)(ws + off);      off += (size_t)B_ * CO * KTOT * 2;      // 75.5 MB
    __bf16* imgpad = (__bf16*)(ws + off);    off += IMGPAD_ELEMS * 2;                // 71.4 MB
    float* style = (float*)(ws + off);       off += (size_t)B_ * CI * 4;
    float* invn  = (float*)(ws + off);       off += (size_t)B_ * CO * 4;
    float* w2    = (float*)(ws + off);       off += (size_t)CO * CI * 4;

    style_kernel<<<dim3(2, B_), 256, 0, stream>>>(w_embs, style_w, style_b, style);
    w2_kernel<<<dim3(1024), 256, 0, stream>>>(conv_w, w2);
    invn_kernel<<<dim3(2, B_), 256, 0, stream>>>(w2, style, invn);
    wmod_kernel<<<dim3(CO / 4, B_), 256, 0, stream>>>(conv_w, style, invn, wmod);
    halo_kernel<<<dim3((B_ * 260 * 64 + 255) / 256), 256, 0, stream>>>(imgpad);
    imgpad_kernel<<<dim3(16, HH, B_), 256, 0, stream>>>(imgs, imgpad);
    conv_kernel<<<dim3(NPIX / BN, CO / BM, B_), 256, 0, stream>>>(
        wmod, imgpad, conv_b, noise, nw, out);
}

// Round 3
// 670.596 us; speedup vs baseline: 1.1608x; 1.1437x over previous
//
#include <hip/hip_runtime.h>
#include <hip/hip_bf16.h>

// Problem constants
#define B_    16
#define CI    512
#define CO    512
#define HH    64
#define WW    64
#define NPIX  4096          // 64*64
#define KTAPS 9
#define KTOT  (CI * KTAPS)  // 4608
#define LEAK  0.2f

// Padded channels-last image: [b][66][66][512] bf16 (1-px halo absorbs SAME pad)
#define PY 66
#define PX 66
#define IMGPAD_ELEMS ((size_t)B_ * PY * PX * CI)

typedef __attribute__((ext_vector_type(8))) __bf16  bf16x8;
typedef __attribute__((ext_vector_type(4))) float   floatx4;

// Direct global->LDS 16B staging (m97 pattern). LDS dest is wave-uniform
// base + lane*16; global addr is per-lane.
__device__ __forceinline__ void load_lds16(const __bf16* g, __bf16* l) {
    __builtin_amdgcn_global_load_lds(
        (const __attribute__((address_space(1))) unsigned int*)g,
        (__attribute__((address_space(3))) unsigned int*)(unsigned int)(uintptr_t)l,
        16, 0, 0);
}

// ---------------------------------------------------------------- prep kernels

// style[b][i] = sum_w w_embs[b][w] * style_w[i][w] + style_b[i] + 1
__global__ void style_kernel(const float* __restrict__ w_embs,
                             const float* __restrict__ style_w,
                             const float* __restrict__ style_b,
                             float* __restrict__ style) {
    int b = blockIdx.y;
    int i = blockIdx.x * 256 + threadIdx.x;
    const float4* we = (const float4*)(w_embs + (size_t)b * 512);
    const float4* sw = (const float4*)(style_w + (size_t)i * 512);
    float acc = 0.f;
    #pragma unroll 8
    for (int k = 0; k < 128; ++k) {
        float4 a = we[k], c = sw[k];
        acc += a.x * c.x + a.y * c.y + a.z * c.z + a.w * c.w;
    }
    style[b * 512 + i] = acc + style_b[i] + 1.0f;
}

// w2[o][i] = sum_tap conv_w[o][i][tap]^2
__global__ void w2_kernel(const float* __restrict__ conv_w, float* __restrict__ w2) {
    int idx = blockIdx.x * 256 + threadIdx.x;   // o*512+i, 262144 total
    const float* p = conv_w + (size_t)idx * 9;
    float s = 0.f;
    #pragma unroll
    for (int t = 0; t < 9; ++t) s += p[t] * p[t];
    w2[idx] = s;
}

// invn[b][o] = 1/sqrt( sum_i w2[o][i] * style[b][i]^2 )
__global__ void invn_kernel(const float* __restrict__ w2,
                            const float* __restrict__ style,
                            float* __restrict__ invn) {
    __shared__ float st2[512];
    int b = blockIdx.y;
    int o = blockIdx.x * 256 + threadIdx.x;
    for (int i = threadIdx.x; i < 512; i += 256) {
        float s = style[b * 512 + i];
        st2[i] = s * s;
    }
    __syncthreads();
    const float* wr = w2 + (size_t)o * 512;
    float acc = 0.f;
    #pragma unroll 8
    for (int i = 0; i < 512; ++i) acc += wr[i] * st2[i];
    invn[b * 512 + o] = 1.0f / sqrtf(acc);
}

// wmod[b][o][tap*512 + i] = bf16( conv_w[o][i][tap] * style[b][i] * invn[b][o] )
// Coalesced: thread owns (o, i0..i0+7); reads 72 contiguous floats, writes 9 x 16B.
__global__ void wmod_kernel(const float* __restrict__ conv_w,
                            const float* __restrict__ style,
                            const float* __restrict__ invn,
                            __bf16* __restrict__ wmod) {
    int b = blockIdx.y;
    int o = blockIdx.x * 4 + (threadIdx.x >> 6);
    int i0 = (threadIdx.x & 63) * 8;
    float inv = invn[b * 512 + o];
    float s[8];
    #pragma unroll
    for (int j = 0; j < 8; ++j) s[j] = style[b * 512 + i0 + j] * inv;
    const float* p = conv_w + ((size_t)o * 512 + i0) * 9;   // 72 contiguous floats
    float w[8][9];
    #pragma unroll
    for (int j = 0; j < 8; ++j)
        #pragma unroll
        for (int t = 0; t < 9; ++t) w[j][t] = p[j * 9 + t];
    __bf16* dstB = wmod + ((size_t)(b * 512 + o)) * KTOT + i0;
    #pragma unroll
    for (int t = 0; t < 9; ++t) {
        bf16x8 v;
        #pragma unroll
        for (int j = 0; j < 8; ++j) v[j] = (__bf16)(w[j][t] * s[j]);
        *(bf16x8*)(dstB + t * 512) = v;
    }
}

// Zero only the halo ring of imgpad (260 px/batch instead of 71 MB memset)
__global__ void halo_kernel(__bf16* __restrict__ imgpad) {
    int t = blockIdx.x * 256 + threadIdx.x;
    if (t >= B_ * 260 * 64) return;
    int c8 = t & 63;
    int rest = t >> 6;
    int px = rest % 260;
    int b = rest / 260;
    int y, x;
    if (px < 66)       { y = 0;  x = px; }
    else if (px < 132) { y = 65; x = px - 66; }
    else { int s = px - 132; y = 1 + (s >> 1); x = (s & 1) * 65; }
    float4 z = {0.f, 0.f, 0.f, 0.f};
    *(float4*)&imgpad[(((size_t)b * PY + y) * PX + x) * 512 + c8 * 8] = z;
}

// NCHW fp32 -> padded channels-last bf16 [b][y][x][i]; interior only
__global__ void imgpad_kernel(const float* __restrict__ imgs,
                              __bf16* __restrict__ imgpad) {
    __shared__ float tile[32][65];
    int ic = blockIdx.x, h = blockIdx.y, b = blockIdx.z;
    int t = threadIdx.x;
    int i0 = ic * 32;
    {
        int li = t >> 3;            // 0..31 channel within chunk
        int w0 = (t & 7) * 8;       // 0..56
        const float* src = imgs + (((size_t)(b * 512 + i0 + li) * 64 + h) * 64 + w0);
        float4 v0 = ((const float4*)src)[0];
        float4 v1 = ((const float4*)src)[1];
        tile[li][w0 + 0] = v0.x; tile[li][w0 + 1] = v0.y;
        tile[li][w0 + 2] = v0.z; tile[li][w0 + 3] = v0.w;
        tile[li][w0 + 4] = v1.x; tile[li][w0 + 5] = v1.y;
        tile[li][w0 + 6] = v1.z; tile[li][w0 + 7] = v1.w;
    }
    __syncthreads();
    {
        int w  = t >> 2;            // 0..63
        int c0 = (t & 3) * 8;       // 0,8,16,24
        bf16x8 v;
        #pragma unroll
        for (int j = 0; j < 8; ++j) v[j] = (__bf16)tile[c0 + j][w];
        __bf16* dst = imgpad + (((size_t)b * PY + (h + 1)) * PX + (w + 1)) * 512 + i0 + c0;
        *(bf16x8*)dst = v;
    }
}

// ---------------------------------------------------------------- main conv

#define BM 128
#define BN 128
#define BK 32
#define NCHUNK 144   // 9 taps * 16 channel-chunks; A k-index = 32*kk (contiguous)

__global__ __launch_bounds__(256, 3) void conv_kernel(
    const __bf16* __restrict__ wmod,
    const __bf16* __restrict__ imgpad,
    const float*  __restrict__ conv_b,
    const float*  __restrict__ noise,
    const float*  __restrict__ nw_p,
    float* __restrict__ out)
{
    // Double-buffered, unpadded, lane-ordered (global_load_lds layout)
    __shared__ __attribute__((aligned(16))) __bf16 As[2][BM * BK];
    __shared__ __attribute__((aligned(16))) __bf16 Bs[2][BN * BK];

    int tid = threadIdx.x;
    int nt = blockIdx.x, mt = blockIdx.y, b = blockIdx.z;
    int n0 = nt * BN, m0 = mt * BM;

    const __bf16* wB = wmod + ((size_t)b * CO + m0) * KTOT;
    const __bf16* iB = imgpad + (size_t)b * PY * PX * CI;

    int lane = tid & 63;
    int wv = tid >> 6;
    int wm = (wv & 1) * 64, wn = (wv >> 1) * 64;
    int q = lane >> 4, r = lane & 15;

    // staging: wave wv stages 16-row segments wv and wv+4 of each tile.
    // lane l -> row = seg*16 + (l>>2), k8 = (l&3)*8  (matches LDS base+lane*16)
    int sRow = lane >> 2;
    int sK8  = (lane & 3) * 8;
    int aRow0 = wv * 16 + sRow;
    int aRow1 = aRow0 + 64;
    const __bf16* aG0 = wB + (size_t)aRow0 * KTOT + sK8;   // + kk*32 each chunk
    const __bf16* aG1 = wB + (size_t)aRow1 * KTOT + sK8;
    int p0 = n0 + aRow0, p1 = n0 + aRow1;
    int h0 = p0 >> 6, w0 = p0 & 63;
    int h1 = p1 >> 6, w1 = p1 & 63;
    // tap(0,0) base; per-tap delta = (dy*PX+dx)*512, per-chunk delta = ic*32
    const __bf16* bG0 = iB + ((size_t)h0 * PX + w0) * 512 + sK8;
    const __bf16* bG1 = iB + ((size_t)h1 * PX + w1) * 512 + sK8;

    int lOff0 = (wv * 16) * BK;          // LDS offsets for this wave's segments
    int lOff1 = (wv * 16 + 64) * BK;

    floatx4 acc[4][4];
    #pragma unroll
    for (int mi = 0; mi < 4; ++mi)
        #pragma unroll
        for (int ni = 0; ni < 4; ++ni)
            acc[mi][ni] = (floatx4)(0.f);

    // prologue: stage chunk 0 into buffer 0
    {
        load_lds16(aG0, &As[0][lOff0]);
        load_lds16(aG1, &As[0][lOff1]);
        load_lds16(bG0, &Bs[0][lOff0]);
        load_lds16(bG1, &Bs[0][lOff1]);
    }

    for (int kk = 0; kk < NCHUNK; ++kk) {
        int cur = kk & 1;
        __syncthreads();   // drains chunk kk's loads (issued last iter) + last iter's ds_reads
        if (kk < NCHUNK - 1) {
            int nxt = kk + 1;
            int tap = nxt >> 4, ic = nxt & 15;
            int dy = tap / 3, dx = tap - 3 * dy;
            int bd = (dy * PX + dx) * 512 + ic * BK;
            load_lds16(aG0 + nxt * BK, &As[cur ^ 1][lOff0]);
            load_lds16(aG1 + nxt * BK, &As[cur ^ 1][lOff1]);
            load_lds16(bG0 + bd,       &Bs[cur ^ 1][lOff0]);
            load_lds16(bG1 + bd,       &Bs[cur ^ 1][lOff1]);
        }
        bf16x8 af[4], bfr[4];
        #pragma unroll
        for (int mi = 0; mi < 4; ++mi)
            af[mi] = *(const bf16x8*)&As[cur][(wm + mi * 16 + r) * BK + q * 8];
        #pragma unroll
        for (int ni = 0; ni < 4; ++ni)
            bfr[ni] = *(const bf16x8*)&Bs[cur][(wn + ni * 16 + r) * BK + q * 8];
        #pragma unroll
        for (int mi = 0; mi < 4; ++mi)
            #pragma unroll
            for (int ni = 0; ni < 4; ++ni)
                acc[mi][ni] = __builtin_amdgcn_mfma_f32_16x16x32_bf16(
                    af[mi], bfr[ni], acc[mi][ni], 0, 0, 0);
    }

    // epilogue: + conv_b + noise*nw, LeakyReLU(0.2)
    float nwv = nw_p[0];
    #pragma unroll
    for (int ni = 0; ni < 4; ++ni) {
        int col = n0 + wn + ni * 16 + r;                 // pixel
        float nz = noise[b * NPIX + col] * nwv;
        #pragma unroll
        for (int mi = 0; mi < 4; ++mi) {
            int rowo = m0 + wm + mi * 16 + q * 4;        // output channel base
            #pragma unroll
            for (int rr = 0; rr < 4; ++rr) {
                float vv = acc[mi][ni][rr] + conv_b[rowo + rr] + nz;
                out[(((size_t)b * CO + rowo + rr) << 12) + col] = vv >= 0.f ? vv : LEAK * vv;
            }
        }
    }
}

// ---------------------------------------------------------------- launch

extern "C" void kernel_launch(void* const* d_in, const int* in_sizes, int n_in,
                              void* d_out, int out_size, void* d_ws, size_t ws_size,
                              hipStream_t stream) {
    const float* imgs    = (const float*)d_in[0];
    const float* w_embs  = (const float*)d_in[1];
    const float* noise   = (const float*)d_in[2];
    const float* conv_w  = (const float*)d_in[3];
    const float* conv_b  = (const float*)d_in[4];
    const float* style_w = (const float*)d_in[5];
    const float* style_b = (const float*)d_in[6];
    const float* nw      = (const float*)d_in[7];
    float* out = (float*)d_out;

    char* ws = (char*)d_ws;
    size_t off = 0;
    __bf16* wmod = (__bf16*)(ws + off);      off += (size_t)B_ * CO * KTOT * 2;      // 75.5 MB
    __bf16* imgpad = (__bf16*)(ws + off);    off += IMGPAD_ELEMS * 2;                // 71.4 MB
    float* style = (float*)(ws + off);       off += (size_t)B_ * CI * 4;
    float* invn  = (float*)(ws + off);       off += (size_t)B_ * CO * 4;
    float* w2    = (float*)(ws + off);       off += (size_t)CO * CI * 4;

    style_kernel<<<dim3(2, B_), 256, 0, stream>>>(w_embs, style_w, style_b, style);
    w2_kernel<<<dim3(1024), 256, 0, stream>>>(conv_w, w2);
    invn_kernel<<<dim3(2, B_), 256, 0, stream>>>(w2, style, invn);
    wmod_kernel<<<dim3(CO / 4, B_), 256, 0, stream>>>(conv_w, style, invn, wmod);
    halo_kernel<<<dim3((B_ * 260 * 64 + 255) / 256), 256, 0, stream>>>(imgpad);
    imgpad_kernel<<<dim3(16, HH, B_), 256, 0, stream>>>(imgs, imgpad);
    conv_kernel<<<dim3(NPIX / BN, CO / BM, B_), 256, 0, stream>>>(
        wmod, imgpad, conv_b, noise, nw, out);
}

// Round 4
// 655.104 us; speedup vs baseline: 1.1882x; 1.0236x over previous
//
#include <hip/hip_runtime.h>
#include <hip/hip_bf16.h>

// Problem constants
#define B_    16
#define CI    512
#define CO    512
#define HH    64
#define WW    64
#define NPIX  4096          // 64*64
#define KTAPS 9
#define KTOT  (CI * KTAPS)  // 4608
#define LEAK  0.2f

// Padded channels-last image: [b][66][66][512] bf16 (1-px halo absorbs SAME pad)
// Holds style-premultiplied image: x[b,y,x,i] * style[b,i]
#define PY 66
#define PX 66
#define IMGPAD_ELEMS ((size_t)B_ * PY * PX * CI)

typedef __attribute__((ext_vector_type(8))) __bf16  bf16x8;
typedef __attribute__((ext_vector_type(4))) float   floatx4;

// Direct global->LDS 16B staging (m97 pattern). LDS dest is wave-uniform
// base + lane*16; global addr is per-lane.
__device__ __forceinline__ void load_lds16(const __bf16* g, __bf16* l) {
    __builtin_amdgcn_global_load_lds(
        (const __attribute__((address_space(1))) unsigned int*)g,
        (__attribute__((address_space(3))) unsigned int*)(unsigned int)(uintptr_t)l,
        16, 0, 0);
}

// ---------------------------------------------------------------- prep kernels

// style[b][i] = sum_w w_embs[b][w] * style_w[i][w] + style_b[i] + 1
__global__ void style_kernel(const float* __restrict__ w_embs,
                             const float* __restrict__ style_w,
                             const float* __restrict__ style_b,
                             float* __restrict__ style) {
    int b = blockIdx.y;
    int i = blockIdx.x * 256 + threadIdx.x;
    const float4* we = (const float4*)(w_embs + (size_t)b * 512);
    const float4* sw = (const float4*)(style_w + (size_t)i * 512);
    float acc = 0.f;
    #pragma unroll 8
    for (int k = 0; k < 128; ++k) {
        float4 a = we[k], c = sw[k];
        acc += a.x * c.x + a.y * c.y + a.z * c.z + a.w * c.w;
    }
    style[b * 512 + i] = acc + style_b[i] + 1.0f;
}

// w2[o][i] = sum_tap conv_w[o][i][tap]^2
__global__ void w2_kernel(const float* __restrict__ conv_w, float* __restrict__ w2) {
    int idx = blockIdx.x * 256 + threadIdx.x;   // o*512+i, 262144 total
    const float* p = conv_w + (size_t)idx * 9;
    float s = 0.f;
    #pragma unroll
    for (int t = 0; t < 9; ++t) s += p[t] * p[t];
    w2[idx] = s;
}

// invn[b][o] = 1/sqrt( sum_i w2[o][i] * style[b][i]^2 )
__global__ void invn_kernel(const float* __restrict__ w2,
                            const float* __restrict__ style,
                            float* __restrict__ invn) {
    __shared__ float st2[512];
    int b = blockIdx.y;
    int o = blockIdx.x * 256 + threadIdx.x;
    for (int i = threadIdx.x; i < 512; i += 256) {
        float s = style[b * 512 + i];
        st2[i] = s * s;
    }
    __syncthreads();
    const float* wr = w2 + (size_t)o * 512;
    float acc = 0.f;
    #pragma unroll 8
    for (int i = 0; i < 512; ++i) acc += wr[i] * st2[i];
    invn[b * 512 + o] = 1.0f / sqrtf(acc);
}

// Shared (batch-independent) bf16 weight, k-contiguous: wsh[o][tap*512 + i]
__global__ void wsh_kernel(const float* __restrict__ conv_w,
                           __bf16* __restrict__ wsh) {
    int o = blockIdx.x * 4 + (threadIdx.x >> 6);
    int i0 = (threadIdx.x & 63) * 8;
    const float* p = conv_w + ((size_t)o * 512 + i0) * 9;   // 72 contiguous floats
    float w[8][9];
    #pragma unroll
    for (int j = 0; j < 8; ++j)
        #pragma unroll
        for (int t = 0; t < 9; ++t) w[j][t] = p[j * 9 + t];
    __bf16* dstB = wsh + (size_t)o * KTOT + i0;
    #pragma unroll
    for (int t = 0; t < 9; ++t) {
        bf16x8 v;
        #pragma unroll
        for (int j = 0; j < 8; ++j) v[j] = (__bf16)w[j][t];
        *(bf16x8*)(dstB + t * 512) = v;
    }
}

// Zero only the halo ring of imgpad (260 px/batch instead of 71 MB memset)
__global__ void halo_kernel(__bf16* __restrict__ imgpad) {
    int t = blockIdx.x * 256 + threadIdx.x;
    if (t >= B_ * 260 * 64) return;
    int c8 = t & 63;
    int rest = t >> 6;
    int px = rest % 260;
    int b = rest / 260;
    int y, x;
    if (px < 66)       { y = 0;  x = px; }
    else if (px < 132) { y = 65; x = px - 66; }
    else { int s = px - 132; y = 1 + (s >> 1); x = (s & 1) * 65; }
    float4 z = {0.f, 0.f, 0.f, 0.f};
    *(float4*)&imgpad[(((size_t)b * PY + y) * PX + x) * 512 + c8 * 8] = z;
}

// NCHW fp32 -> padded channels-last bf16 [b][y][x][i], premultiplied by style[b][i]
__global__ void imgpad_kernel(const float* __restrict__ imgs,
                              const float* __restrict__ style,
                              __bf16* __restrict__ imgpad) {
    __shared__ float tile[32][65];
    int ic = blockIdx.x, h = blockIdx.y, b = blockIdx.z;
    int t = threadIdx.x;
    int i0 = ic * 32;
    {
        int li = t >> 3;            // 0..31 channel within chunk
        int w0 = (t & 7) * 8;       // 0..56
        const float* src = imgs + (((size_t)(b * 512 + i0 + li) * 64 + h) * 64 + w0);
        float4 v0 = ((const float4*)src)[0];
        float4 v1 = ((const float4*)src)[1];
        tile[li][w0 + 0] = v0.x; tile[li][w0 + 1] = v0.y;
        tile[li][w0 + 2] = v0.z; tile[li][w0 + 3] = v0.w;
        tile[li][w0 + 4] = v1.x; tile[li][w0 + 5] = v1.y;
        tile[li][w0 + 6] = v1.z; tile[li][w0 + 7] = v1.w;
    }
    __syncthreads();
    {
        int w  = t >> 2;            // 0..63
        int c0 = (t & 3) * 8;       // 0,8,16,24
        float st[8];
        #pragma unroll
        for (int j = 0; j < 8; ++j) st[j] = style[b * 512 + i0 + c0 + j];
        bf16x8 v;
        #pragma unroll
        for (int j = 0; j < 8; ++j) v[j] = (__bf16)(tile[c0 + j][w] * st[j]);
        __bf16* dst = imgpad + (((size_t)b * PY + (h + 1)) * PX + (w + 1)) * 512 + i0 + c0;
        *(bf16x8*)dst = v;
    }
}

// ---------------------------------------------------------------- main conv

#define BM 128
#define BN 128
#define BK 32
#define NCHUNK 144   // 9 taps * 16 channel-chunks; A k-index = 32*kk (contiguous)

// out[b,o,p] = leaky( invn[b,o] * (wsh[o,:] . ximg[b,p,:]) + conv_b[o] + noise*nw )
__global__ __launch_bounds__(256, 3) void conv_kernel(
    const __bf16* __restrict__ wsh,
    const __bf16* __restrict__ imgpad,
    const float*  __restrict__ invn,
    const float*  __restrict__ conv_b,
    const float*  __restrict__ noise,
    const float*  __restrict__ nw_p,
    float* __restrict__ out)
{
    // Double-buffered, unpadded, lane-ordered (global_load_lds layout).
    // k-group slot XOR-swizzled by (row>>2)&3 to break the 8-way bank conflict
    // of 64B-strided ds_read_b128 fragment reads (applied at stage time by
    // permuting WHICH global group each lane fetches; LDS addr stays lane*16).
    __shared__ __attribute__((aligned(16))) __bf16 As[2][BM * BK];
    __shared__ __attribute__((aligned(16))) __bf16 Bs[2][BN * BK];

    int tid = threadIdx.x;
    int nt = blockIdx.x, mt = blockIdx.y, b = blockIdx.z;
    int n0 = nt * BN, m0 = mt * BM;

    const __bf16* wB = wsh + (size_t)m0 * KTOT;          // batch-independent A
    const __bf16* iB = imgpad + (size_t)b * PY * PX * CI;

    int lane = tid & 63;
    int wv = tid >> 6;
    int wm = (wv & 1) * 64, wn = (wv >> 1) * 64;
    int q = lane >> 4, r = lane & 15;

    // staging: wave wv stages 16-row segments wv and wv+4 of each tile.
    // lane l -> row = seg*16 + (l>>2); fetched k-group = (l&3) ^ ((l>>4)&3)
    int sRow = lane >> 2;
    int sK8  = (((lane & 3) ^ ((lane >> 4) & 3))) * 8;   // swizzled global group
    int aRow0 = wv * 16 + sRow;
    int aRow1 = aRow0 + 64;
    const __bf16* aG0 = wB + (size_t)aRow0 * KTOT + sK8;   // + kk*32 each chunk
    const __bf16* aG1 = wB + (size_t)aRow1 * KTOT + sK8;
    int p0 = n0 + aRow0, p1 = n0 + aRow1;
    int h0 = p0 >> 6, w0 = p0 & 63;
    int h1 = p1 >> 6, w1 = p1 & 63;
    // tap(0,0) base; per-tap delta = (dy*PX+dx)*512, per-chunk delta = ic*32
    const __bf16* bG0 = iB + ((size_t)h0 * PX + w0) * 512 + sK8;
    const __bf16* bG1 = iB + ((size_t)h1 * PX + w1) * 512 + sK8;

    int lOff0 = (wv * 16) * BK;          // LDS offsets for this wave's segments
    int lOff1 = (wv * 16 + 64) * BK;

    floatx4 acc[4][4];
    #pragma unroll
    for (int mi = 0; mi < 4; ++mi)
        #pragma unroll
        for (int ni = 0; ni < 4; ++ni)
            acc[mi][ni] = (floatx4)(0.f);

    // fragment-read slot for this lane: q ^ ((r>>2)&3)
    int fSlot = (q ^ ((r >> 2) & 3)) * 8;

    // prologue: stage chunk 0 into buffer 0
    load_lds16(aG0, &As[0][lOff0]);
    load_lds16(aG1, &As[0][lOff1]);
    load_lds16(bG0, &Bs[0][lOff0]);
    load_lds16(bG1, &Bs[0][lOff1]);

    for (int kk = 0; kk < NCHUNK; ++kk) {
        int cur = kk & 1;
        __syncthreads();   // drains chunk kk's loads (issued last iter) + last iter's ds_reads
        if (kk < NCHUNK - 1) {
            int nxt = kk + 1;
            int tap = nxt >> 4, ic = nxt & 15;
            int dy = tap / 3, dx = tap - 3 * dy;
            int bd = (dy * PX + dx) * 512 + ic * BK;
            load_lds16(aG0 + nxt * BK, &As[cur ^ 1][lOff0]);
            load_lds16(aG1 + nxt * BK, &As[cur ^ 1][lOff1]);
            load_lds16(bG0 + bd,       &Bs[cur ^ 1][lOff0]);
            load_lds16(bG1 + bd,       &Bs[cur ^ 1][lOff1]);
        }
        bf16x8 af[4], bfr[4];
        #pragma unroll
        for (int mi = 0; mi < 4; ++mi)
            af[mi] = *(const bf16x8*)&As[cur][(wm + mi * 16 + r) * BK + fSlot];
        #pragma unroll
        for (int ni = 0; ni < 4; ++ni)
            bfr[ni] = *(const bf16x8*)&Bs[cur][(wn + ni * 16 + r) * BK + fSlot];
        #pragma unroll
        for (int mi = 0; mi < 4; ++mi)
            #pragma unroll
            for (int ni = 0; ni < 4; ++ni)
                acc[mi][ni] = __builtin_amdgcn_mfma_f32_16x16x32_bf16(
                    af[mi], bfr[ni], acc[mi][ni], 0, 0, 0);
    }

    // epilogue: * invn[b,o] + conv_b + noise*nw, LeakyReLU(0.2)
    float nwv = nw_p[0];
    #pragma unroll
    for (int ni = 0; ni < 4; ++ni) {
        int col = n0 + wn + ni * 16 + r;                 // pixel
        float nz = noise[b * NPIX + col] * nwv;
        #pragma unroll
        for (int mi = 0; mi < 4; ++mi) {
            int rowo = m0 + wm + mi * 16 + q * 4;        // output channel base
            #pragma unroll
            for (int rr = 0; rr < 4; ++rr) {
                float sc = invn[b * 512 + rowo + rr];
                float vv = acc[mi][ni][rr] * sc + conv_b[rowo + rr] + nz;
                out[(((size_t)b * CO + rowo + rr) << 12) + col] = vv >= 0.f ? vv : LEAK * vv;
            }
        }
    }
}

// ---------------------------------------------------------------- launch

extern "C" void kernel_launch(void* const* d_in, const int* in_sizes, int n_in,
                              void* d_out, int out_size, void* d_ws, size_t ws_size,
                              hipStream_t stream) {
    const float* imgs    = (const float*)d_in[0];
    const float* w_embs  = (const float*)d_in[1];
    const float* noise   = (const float*)d_in[2];
    const float* conv_w  = (const float*)d_in[3];
    const float* conv_b  = (const float*)d_in[4];
    const float* style_w = (const float*)d_in[5];
    const float* style_b = (const float*)d_in[6];
    const float* nw      = (const float*)d_in[7];
    float* out = (float*)d_out;

    char* ws = (char*)d_ws;
    size_t off = 0;
    __bf16* wsh = (__bf16*)(ws + off);       off += (size_t)CO * KTOT * 2;           // 4.7 MB
    __bf16* imgpad = (__bf16*)(ws + off);    off += IMGPAD_ELEMS * 2;                // 71.4 MB
    float* style = (float*)(ws + off);       off += (size_t)B_ * CI * 4;
    float* invn  = (float*)(ws + off);       off += (size_t)B_ * CO * 4;
    float* w2    = (float*)(ws + off);       off += (size_t)CO * CI * 4;

    style_kernel<<<dim3(2, B_), 256, 0, stream>>>(w_embs, style_w, style_b, style);
    w2_kernel<<<dim3(1024), 256, 0, stream>>>(conv_w, w2);
    invn_kernel<<<dim3(2, B_), 256, 0, stream>>>(w2, style, invn);
    wsh_kernel<<<dim3(CO / 4), 256, 0, stream>>>(conv_w, wsh);
    halo_kernel<<<dim3((B_ * 260 * 64 + 255) / 256), 256, 0, stream>>>(imgpad);
    imgpad_kernel<<<dim3(16, HH, B_), 256, 0, stream>>>(imgs, style, imgpad);
    conv_kernel<<<dim3(NPIX / BN, CO / BM, B_), 256, 0, stream>>>(
        wsh, imgpad, invn, conv_b, noise, nw, out);
}